// Round 16
// baseline (303.719 us; speedup 1.0000x reference)
//
#include <hip/hip_runtime.h>

// NConv depth-completion net, fp32. R16 = R15 + s_setprio(1) around the
// pk_fma compute clusters (T5): 6 independent blocks/CU alternate stage vs
// compute phases -> priority boost lets compute-phase waves win issue
// arbitration (mechanism-matched: attn-style phase diversity, not GEMM
// lockstep). All R15 structure frozen (SGPR weights via prepw table in
// d_out head, async-stage, parity LDS, packed float4 globals, fused
// pool/w7, 32x16 tiles).

#define EPSN 1e-20f

typedef float v2f __attribute__((ext_vector_type(2)));

__device__ __forceinline__ float softplusf(float x) {
    return fmaxf(x, 0.f) + log1pf(expf(-fabsf(x)));
}
__device__ __forceinline__ float rcpf(float x) { return __builtin_amdgcn_rcpf(x); }

// acc: a[0]={den0,den1} a[1]={den2,den3} a[2]={nom0,nom1} a[3]={nom2,nom3}
__device__ __forceinline__ void tap4(v2f v, v2f w01, v2f w23, v2f* a)
{
    asm("v_pk_fma_f32 %0, %1, %2, %0 op_sel:[0,0,0] op_sel_hi:[1,0,1]"
        : "+v"(a[0]) : "s"(w01), "v"(v));
    asm("v_pk_fma_f32 %0, %1, %2, %0 op_sel:[0,0,0] op_sel_hi:[1,0,1]"
        : "+v"(a[1]) : "s"(w23), "v"(v));
    asm("v_pk_fma_f32 %0, %1, %2, %0 op_sel:[0,1,0] op_sel_hi:[1,1,1]"
        : "+v"(a[2]) : "s"(w01), "v"(v));
    asm("v_pk_fma_f32 %0, %1, %2, %0 op_sel:[0,1,0] op_sel_hi:[1,1,1]"
        : "+v"(a[3]) : "s"(w23), "v"(v));
}
#define TAPW(W, VA, VB)                                                     \
    { v2f w01_ = {(W).x, (W).y}, w23_ = {(W).z, (W).w};                     \
      tap4((VA), w01_, w23_, aA); tap4((VB), w01_, w23_, aB); }

#define NC_EPI(A, XO, CO)                                            \
    XO.x = A[2].x*rcpf(A[0].x+EPSN)+bias.x; CO.x = A[0].x*rs0;       \
    XO.y = A[2].y*rcpf(A[0].y+EPSN)+bias.y; CO.y = A[0].y*rs1;       \
    XO.z = A[3].x*rcpf(A[1].x+EPSN)+bias.z; CO.z = A[1].x*rs2;       \
    XO.w = A[3].y*rcpf(A[1].y+EPSN)+bias.w; CO.w = A[1].y*rs3;

#define NC_STORE_PACKED(HOUT, WOUT)                                         \
    {                                                                       \
        const int oh = oh0 + ty, ow = ow0 + 2 * tx;                         \
        if (oh < (HOUT) && ow < (WOUT)) {                                   \
            float4 bias = g_bias, ssum = g_sum;                             \
            float rs0=rcpf(ssum.x), rs1=rcpf(ssum.y),                       \
                  rs2=rcpf(ssum.z), rs3=rcpf(ssum.w);                       \
            size_t t = ((size_t)b * (HOUT) + oh) * (WOUT) + ow;             \
            float4 xo, co;                                                  \
            NC_EPI(aA, xo, co)                                              \
            xout4[t] = xo; cout4[t] = co;                                   \
            if (ow + 1 < (WOUT)) {                                          \
                NC_EPI(aB, xo, co)                                          \
                xout4[t+1] = xo; cout4[t+1] = co;                           \
            }                                                               \
        }                                                                   \
    }

#define STAGE_WRITE(SDE, SDO, LY, J, CA, XA, CB, XB)                 \
    SDE[0][LY][J] = (v2f){(CA).x, (XA).x * (CA).x};                  \
    SDE[1][LY][J] = (v2f){(CA).y, (XA).y * (CA).y};                  \
    SDE[2][LY][J] = (v2f){(CA).z, (XA).z * (CA).z};                  \
    SDE[3][LY][J] = (v2f){(CA).w, (XA).w * (CA).w};                  \
    SDO[0][LY][J] = (v2f){(CB).x, (XB).x * (CB).x};                  \
    SDO[1][LY][J] = (v2f){(CB).y, (XB).y * (CB).y};                  \
    SDO[2][LY][J] = (v2f){(CB).z, (XB).z * (CB).z};                  \
    SDO[3][LY][J] = (v2f){(CB).w, (XB).w * (CB).w};

// WP layout (float4 index):
//  w1:0(25) sum:25 bias:26 | w2:27(100) 127 128 | w3:129(100) 229 230
//  w4:231(72) 303 304 | w5:305(72) 377 378 | w6:379(72) 451 452
//  w65:453(36) 489 490 | w7sp:491 b7:492  -- total 493 float4 = 7888 B

__global__ __launch_bounds__(256) void prepw(
    const float* __restrict__ w1, const float* __restrict__ b1,
    const float* __restrict__ w2, const float* __restrict__ b2,
    const float* __restrict__ w3, const float* __restrict__ b3,
    const float* __restrict__ w4, const float* __restrict__ b4,
    const float* __restrict__ w5, const float* __restrict__ b5,
    const float* __restrict__ w6, const float* __restrict__ b6,
    const float* __restrict__ w65, const float* __restrict__ b65,
    const float* __restrict__ w7, const float* __restrict__ b7,
    float4* __restrict__ WP)
{
    const int tid = threadIdx.x;
    if (tid < 25)  WP[0 + tid]   = make_float4(softplusf(w1[tid]),  softplusf(w1[25 + tid]),
                                               softplusf(w1[50 + tid]), softplusf(w1[75 + tid]));
    if (tid < 100) WP[27 + tid]  = make_float4(softplusf(w2[tid]),  softplusf(w2[100 + tid]),
                                               softplusf(w2[200 + tid]), softplusf(w2[300 + tid]));
    if (tid < 100) WP[129 + tid] = make_float4(softplusf(w3[tid]),  softplusf(w3[100 + tid]),
                                               softplusf(w3[200 + tid]), softplusf(w3[300 + tid]));
    if (tid < 72)  WP[231 + tid] = make_float4(softplusf(w4[tid]),  softplusf(w4[72 + tid]),
                                               softplusf(w4[144 + tid]), softplusf(w4[216 + tid]));
    if (tid < 72)  WP[305 + tid] = make_float4(softplusf(w5[tid]),  softplusf(w5[72 + tid]),
                                               softplusf(w5[144 + tid]), softplusf(w5[216 + tid]));
    if (tid < 72)  WP[379 + tid] = make_float4(softplusf(w6[tid]),  softplusf(w6[72 + tid]),
                                               softplusf(w6[144 + tid]), softplusf(w6[216 + tid]));
    if (tid < 36)  WP[453 + tid] = make_float4(softplusf(w65[tid]), softplusf(w65[36 + tid]),
                                               softplusf(w65[72 + tid]), softplusf(w65[108 + tid]));
    if (tid == 0) {
        WP[26]  = make_float4(b1[0], b1[1], b1[2], b1[3]);
        WP[128] = make_float4(b2[0], b2[1], b2[2], b2[3]);
        WP[230] = make_float4(b3[0], b3[1], b3[2], b3[3]);
        WP[304] = make_float4(b4[0], b4[1], b4[2], b4[3]);
        WP[378] = make_float4(b5[0], b5[1], b5[2], b5[3]);
        WP[452] = make_float4(b6[0], b6[1], b6[2], b6[3]);
        WP[490] = make_float4(b65[0], b65[1], b65[2], b65[3]);
        WP[491] = make_float4(softplusf(w7[0]), softplusf(w7[1]),
                              softplusf(w7[2]), softplusf(w7[3]));
        WP[492] = make_float4(b7[0], 0.f, 0.f, 0.f);
    }
    __syncthreads();
    int base = -1, cnt = 0;
    if      (tid == 0) { base = 0;   cnt = 25;  }
    else if (tid == 1) { base = 27;  cnt = 100; }
    else if (tid == 2) { base = 129; cnt = 100; }
    else if (tid == 3) { base = 231; cnt = 72;  }
    else if (tid == 4) { base = 305; cnt = 72;  }
    else if (tid == 5) { base = 379; cnt = 72;  }
    else if (tid == 6) { base = 453; cnt = 36;  }
    if (base >= 0) {
        float4 s = make_float4(0.f, 0.f, 0.f, 0.f);
        for (int i = 0; i < cnt; ++i) {
            float4 w = WP[base + i];
            s.x += w.x; s.y += w.y; s.z += w.z; s.w += w.w;
        }
        WP[base + cnt] = s;
    }
}

// ---------------------------------------------------------------------------
// First 5x5 nconv: planar S in (c0 = S>0.01), packed out. Weights WP[0..].
// ---------------------------------------------------------------------------
__global__ __launch_bounds__(256) void nconv5_first(
    const float* __restrict__ S, const float4* __restrict__ WP,
    float4* __restrict__ xout4, float4* __restrict__ cout4,
    int Hh, int Ww)
{
    __shared__ v2f sdE[20][19], sdO[20][19];
    const int b = blockIdx.z;
    const int oh0 = blockIdx.y * 16, ow0 = blockIdx.x * 32;
    const int tx = threadIdx.x, ty = threadIdx.y, tid = ty * 16 + tx;

    const float4 g_sum = WP[25], g_bias = WP[26];

    for (int i = tid; i < 20 * 18; i += 256) {
        int ly = i / 18, j = i - ly * 18;
        int ih = oh0 - 2 + ly, iw = ow0 - 2 + 2 * j;
        float s0 = 0.f, s1 = 0.f;
        if ((unsigned)ih < (unsigned)Hh && iw >= 0 && iw < Ww - 1) {
            float2 t = *(const float2*)&S[((size_t)b * Hh + ih) * Ww + iw];
            s0 = t.x; s1 = t.y;
        }
        float c0 = (s0 > 0.01f) ? 1.f : 0.f;
        float c1 = (s1 > 0.01f) ? 1.f : 0.f;
        sdE[ly][j] = (v2f){c0, s0 * c0};
        sdO[ly][j] = (v2f){c1, s1 * c1};
    }
    __syncthreads();

    __builtin_amdgcn_s_setprio(1);
    v2f aA[4] = {}, aB[4] = {};
    #pragma unroll
    for (int kj = 0; kj < 5; ++kj) {
        const v2f* rE = &sdE[ty + kj][tx];
        const v2f* rO = &sdO[ty + kj][tx];
        v2f e0 = rE[0], o0 = rO[0], e1 = rE[1], o1 = rO[1], e2 = rE[2], o2 = rO[2];
        const float4* wp = WP + kj * 5;
        float4 W0 = wp[0], W1 = wp[1], W2 = wp[2], W3 = wp[3], W4 = wp[4];
        TAPW(W0, e0, o0)
        TAPW(W1, o0, e1)
        TAPW(W2, e1, o1)
        TAPW(W3, o1, e2)
        TAPW(W4, e2, o2)
    }
    __builtin_amdgcn_s_setprio(0);
    NC_STORE_PACKED(Hh, Ww)
}

// ---------------------------------------------------------------------------
// 5x5 nconv, CI=4, packed. Async-stage. Weights WP[wb..] (wb=27 or 129).
// POOL: fused 2x2 argmax pool.
// ---------------------------------------------------------------------------
template<bool POOL>
__global__ __launch_bounds__(256) void nconv5p4(
    const float4* __restrict__ xin4, const float4* __restrict__ cin4,
    const float4* __restrict__ WP, int wb,
    float4* __restrict__ xout4, float4* __restrict__ cout4,
    float4* __restrict__ xo_p, float4* __restrict__ co_p,
    int Hh, int Ww)
{
    __shared__ v2f sdE[4][20][19], sdO[4][20][19];
    const int b = blockIdx.z;
    const int oh0 = blockIdx.y * 16, ow0 = blockIdx.x * 32;
    const int tx = threadIdx.x, ty = threadIdx.y, tid = ty * 16 + tx;

    const float4 g_sum = WP[wb + 100], g_bias = WP[wb + 101];

    const float4 z = make_float4(0.f, 0.f, 0.f, 0.f);
    float4 cA0 = z, xA0 = z, cB0 = z, xB0 = z;
    float4 cA1 = z, xA1 = z, cB1 = z, xB1 = z;
    const bool t1ok = tid < 104;
    {
        int ly = tid / 18, j = tid - (tid / 18) * 18;
        int ih = oh0 - 2 + ly, iw = ow0 - 2 + 2 * j;
        if ((unsigned)ih < (unsigned)Hh) {
            size_t rb = ((size_t)b * Hh + ih) * Ww;
            if ((unsigned)iw < (unsigned)Ww)       { cA0 = cin4[rb + iw];     xA0 = xin4[rb + iw]; }
            if ((unsigned)(iw + 1) < (unsigned)Ww) { cB0 = cin4[rb + iw + 1]; xB0 = xin4[rb + iw + 1]; }
        }
    }
    if (t1ok) {
        int i = tid + 256;
        int ly = i / 18, j = i - ly * 18;
        int ih = oh0 - 2 + ly, iw = ow0 - 2 + 2 * j;
        if ((unsigned)ih < (unsigned)Hh) {
            size_t rb = ((size_t)b * Hh + ih) * Ww;
            if ((unsigned)iw < (unsigned)Ww)       { cA1 = cin4[rb + iw];     xA1 = xin4[rb + iw]; }
            if ((unsigned)(iw + 1) < (unsigned)Ww) { cB1 = cin4[rb + iw + 1]; xB1 = xin4[rb + iw + 1]; }
        }
    }
    {
        int ly = tid / 18, j = tid - (tid / 18) * 18;
        STAGE_WRITE(sdE, sdO, ly, j, cA0, xA0, cB0, xB0)
    }
    if (t1ok) {
        int i = tid + 256;
        int ly = i / 18, j = i - ly * 18;
        STAGE_WRITE(sdE, sdO, ly, j, cA1, xA1, cB1, xB1)
    }
    __syncthreads();

    __builtin_amdgcn_s_setprio(1);
    v2f aA[4] = {}, aB[4] = {};
    #pragma unroll 1
    for (int ci = 0; ci < 4; ++ci) {
        const float4* wp = WP + wb + ci * 25;
        #pragma unroll
        for (int kj = 0; kj < 5; ++kj) {
            const v2f* rE = &sdE[ci][ty + kj][tx];
            const v2f* rO = &sdO[ci][ty + kj][tx];
            v2f e0 = rE[0], o0 = rO[0], e1 = rE[1], o1 = rO[1], e2 = rE[2], o2 = rO[2];
            float4 W0 = wp[kj * 5], W1 = wp[kj * 5 + 1], W2 = wp[kj * 5 + 2],
                   W3 = wp[kj * 5 + 3], W4 = wp[kj * 5 + 4];
            TAPW(W0, e0, o0)
            TAPW(W1, o0, e1)
            TAPW(W2, e1, o1)
            TAPW(W3, o1, e2)
            TAPW(W4, e2, o2)
        }
    }
    __builtin_amdgcn_s_setprio(0);

    const int oh = oh0 + ty, ow = ow0 + 2 * tx;
    float4 bias = g_bias, ssum = g_sum;
    float rs0 = rcpf(ssum.x), rs1 = rcpf(ssum.y),
          rs2 = rcpf(ssum.z), rs3 = rcpf(ssum.w);
    float4 xoA, coA, xoB, coB;
    NC_EPI(aA, xoA, coA)
    NC_EPI(aB, xoB, coB)
    const bool rowok = oh < Hh, colA = ow < Ww, colB = ow + 1 < Ww;
    if (rowok && colA) {
        size_t t = ((size_t)b * Hh + oh) * Ww + ow;
        xout4[t] = xoA; cout4[t] = coA;
        if (colB) { xout4[t + 1] = xoB; cout4[t + 1] = coB; }
    }
    if (POOL) {
        float4 cb = coA, xb = xoA;
        if (coB.x > cb.x) { cb.x = coB.x; xb.x = xoB.x; }
        if (coB.y > cb.y) { cb.y = coB.y; xb.y = xoB.y; }
        if (coB.z > cb.z) { cb.z = coB.z; xb.z = xoB.z; }
        if (coB.w > cb.w) { cb.w = coB.w; xb.w = xoB.w; }
        float4 cb2, xb2;
        cb2.x = __shfl_down(cb.x, 16); xb2.x = __shfl_down(xb.x, 16);
        cb2.y = __shfl_down(cb.y, 16); xb2.y = __shfl_down(xb.y, 16);
        cb2.z = __shfl_down(cb.z, 16); xb2.z = __shfl_down(xb.z, 16);
        cb2.w = __shfl_down(cb.w, 16); xb2.w = __shfl_down(xb.w, 16);
        if (!(ty & 1) && rowok && colA) {
            if (cb2.x > cb.x) { cb.x = cb2.x; xb.x = xb2.x; }
            if (cb2.y > cb.y) { cb.y = cb2.y; xb.y = xb2.y; }
            if (cb2.z > cb.z) { cb.z = cb2.z; xb.z = xb2.z; }
            if (cb2.w > cb.w) { cb.w = cb2.w; xb.w = xb2.w; }
            cb.x *= 0.25f; cb.y *= 0.25f; cb.z *= 0.25f; cb.w *= 0.25f;
            size_t tp = ((size_t)b * (Hh >> 1) + (oh >> 1)) * (Ww >> 1) + (ow >> 1);
            xo_p[tp] = xb; co_p[tp] = cb;
        }
    }
}

// ---------------------------------------------------------------------------
// 3x3 nconv over concat{direct, up2}. Async-stage. Weights WP[wb..] (72).
// UP_FIRST: up occupies weight channels 0-3 (w6) else 4-7 (w4,w5).
// ---------------------------------------------------------------------------
template<bool UP_FIRST, int PAD>
__global__ __launch_bounds__(256) void nconv3cat(
    const float4* __restrict__ xd4, const float4* __restrict__ cd4,
    const float4* __restrict__ xu4, const float4* __restrict__ cu4,
    const float4* __restrict__ WP, int wb,
    float4* __restrict__ xout4, float4* __restrict__ cout4,
    int Hin, int Win)
{
    __shared__ v2f sdE[4][18][18], sdO[4][18][18];
    __shared__ v2f sup[4][10][19];
    const int Hout = Hin - 2 + 2 * PAD, Wout = Win - 2 + 2 * PAD;
    const int Hu = Hin / 2, Wu = Win / 2;
    const int b = blockIdx.z;
    const int oh0 = blockIdx.y * 16, ow0 = blockIdx.x * 32;
    const int tx = threadIdx.x, ty = threadIdx.y, tid = ty * 16 + tx;

    const float4 g_sum = WP[wb + 72], g_bias = WP[wb + 73];

    const float4 z = make_float4(0.f, 0.f, 0.f, 0.f);
    float4 cA0 = z, xA0 = z, cB0 = z, xB0 = z;
    float4 cA1 = z, xA1 = z, cB1 = z, xB1 = z;
    float4 cU = z, xU = z;
    const bool t1ok = tid < 50, upok = tid < 180;
    {
        int ly = tid / 17, j = tid - (tid / 17) * 17;
        int ih = oh0 - PAD + ly, iw = ow0 - PAD + 2 * j;
        if ((unsigned)ih < (unsigned)Hin) {
            size_t rb = ((size_t)b * Hin + ih) * Win;
            if ((unsigned)iw < (unsigned)Win)       { cA0 = cd4[rb + iw];     xA0 = xd4[rb + iw]; }
            if ((unsigned)(iw + 1) < (unsigned)Win) { cB0 = cd4[rb + iw + 1]; xB0 = xd4[rb + iw + 1]; }
        }
    }
    if (t1ok) {
        int i = tid + 256;
        int ly = i / 17, j = i - ly * 17;
        int ih = oh0 - PAD + ly, iw = ow0 - PAD + 2 * j;
        if ((unsigned)ih < (unsigned)Hin) {
            size_t rb = ((size_t)b * Hin + ih) * Win;
            if ((unsigned)iw < (unsigned)Win)       { cA1 = cd4[rb + iw];     xA1 = xd4[rb + iw]; }
            if ((unsigned)(iw + 1) < (unsigned)Win) { cB1 = cd4[rb + iw + 1]; xB1 = xd4[rb + iw + 1]; }
        }
    }
    const int ru0 = (oh0 - PAD) >> 1, cu0 = (ow0 - PAD) >> 1;
    if (upok) {
        int r = tid / 18, k = tid - (tid / 18) * 18;
        int ur = ru0 + r, uc = cu0 + k;
        if ((unsigned)ur < (unsigned)Hu && (unsigned)uc < (unsigned)Wu) {
            size_t t = ((size_t)b * Hu + ur) * Wu + uc;
            cU = cu4[t]; xU = xu4[t];
        }
    }
    {
        int ly = tid / 17, j = tid - (tid / 17) * 17;
        STAGE_WRITE(sdE, sdO, ly, j, cA0, xA0, cB0, xB0)
    }
    if (t1ok) {
        int i = tid + 256;
        int ly = i / 17, j = i - ly * 17;
        STAGE_WRITE(sdE, sdO, ly, j, cA1, xA1, cB1, xB1)
    }
    if (upok) {
        int r = tid / 18, k = tid - (tid / 18) * 18;
        sup[0][r][k] = (v2f){cU.x, xU.x * cU.x};
        sup[1][r][k] = (v2f){cU.y, xU.y * cU.y};
        sup[2][r][k] = (v2f){cU.z, xU.z * cU.z};
        sup[3][r][k] = (v2f){cU.w, xU.w * cU.w};
    }
    __syncthreads();

    __builtin_amdgcn_s_setprio(1);
    v2f aA[4] = {}, aB[4] = {};
    #pragma unroll 1
    for (int ci = 0; ci < 4; ++ci) {
        const int chD = UP_FIRST ? ci + 4 : ci;
        const int chU = UP_FIRST ? ci : ci + 4;
        #pragma unroll
        for (int kj = 0; kj < 3; ++kj) {
            const v2f* rE = &sdE[ci][ty + kj][tx];
            const v2f* rO = &sdO[ci][ty + kj][tx];
            v2f e0 = rE[0], o0 = rO[0], e1 = rE[1], o1 = rO[1];
            const float4* wp = WP + wb + chD * 9 + kj * 3;
            float4 W0 = wp[0], W1 = wp[1], W2 = wp[2];
            TAPW(W0, e0, o0)
            TAPW(W1, o0, e1)
            TAPW(W2, e1, o1)
        }
        #pragma unroll
        for (int kj = 0; kj < 3; ++kj) {
            int lyu = (ty + kj + PAD) >> 1;
            const v2f* ru = &sup[ci][lyu][tx];
            v2f u0 = ru[0], u1 = ru[1];
            v2f q0, q1, q2, q3;
            if (PAD == 1) {
                v2f u2 = ru[2];
                q0 = u0; q1 = u1; q2 = u1; q3 = u2;
            } else {
                q0 = u0; q1 = u0; q2 = u1; q3 = u1;
            }
            const float4* wp = WP + wb + chU * 9 + kj * 3;
            float4 W0 = wp[0], W1 = wp[1], W2 = wp[2];
            TAPW(W0, q0, q1)
            TAPW(W1, q1, q2)
            TAPW(W2, q2, q3)
        }
    }
    __builtin_amdgcn_s_setprio(0);
    NC_STORE_PACKED(Hout, Wout)
}

// ---------------------------------------------------------------------------
// 3x3 nconv 4->4 pad=1 (w65) + 1x1 nconv (w7) -> scalar z. Async-stage.
// ---------------------------------------------------------------------------
__global__ __launch_bounds__(256) void nconv3p_w7(
    const float4* __restrict__ xin4, const float4* __restrict__ cin4,
    const float4* __restrict__ WP,
    float* __restrict__ zout,
    int Hh, int Ww)
{
    __shared__ v2f sdE[4][18][18], sdO[4][18][18];
    const int b = blockIdx.z;
    const int oh0 = blockIdx.y * 16, ow0 = blockIdx.x * 32;
    const int tx = threadIdx.x, ty = threadIdx.y, tid = ty * 16 + tx;

    const float4 g_sum = WP[489], g_bias = WP[490];
    const float4 w7 = WP[491];
    const float b7 = WP[492].x;

    const float4 z = make_float4(0.f, 0.f, 0.f, 0.f);
    float4 cA0 = z, xA0 = z, cB0 = z, xB0 = z;
    float4 cA1 = z, xA1 = z, cB1 = z, xB1 = z;
    const bool t1ok = tid < 50;
    {
        int ly = tid / 17, j = tid - (tid / 17) * 17;
        int ih = oh0 - 1 + ly, iw = ow0 - 1 + 2 * j;
        if ((unsigned)ih < (unsigned)Hh) {
            size_t rb = ((size_t)b * Hh + ih) * Ww;
            if ((unsigned)iw < (unsigned)Ww)       { cA0 = cin4[rb + iw];     xA0 = xin4[rb + iw]; }
            if ((unsigned)(iw + 1) < (unsigned)Ww) { cB0 = cin4[rb + iw + 1]; xB0 = xin4[rb + iw + 1]; }
        }
    }
    if (t1ok) {
        int i = tid + 256;
        int ly = i / 17, j = i - ly * 17;
        int ih = oh0 - 1 + ly, iw = ow0 - 1 + 2 * j;
        if ((unsigned)ih < (unsigned)Hh) {
            size_t rb = ((size_t)b * Hh + ih) * Ww;
            if ((unsigned)iw < (unsigned)Ww)       { cA1 = cin4[rb + iw];     xA1 = xin4[rb + iw]; }
            if ((unsigned)(iw + 1) < (unsigned)Ww) { cB1 = cin4[rb + iw + 1]; xB1 = xin4[rb + iw + 1]; }
        }
    }
    {
        int ly = tid / 17, j = tid - (tid / 17) * 17;
        STAGE_WRITE(sdE, sdO, ly, j, cA0, xA0, cB0, xB0)
    }
    if (t1ok) {
        int i = tid + 256;
        int ly = i / 17, j = i - ly * 17;
        STAGE_WRITE(sdE, sdO, ly, j, cA1, xA1, cB1, xB1)
    }
    __syncthreads();

    __builtin_amdgcn_s_setprio(1);
    v2f aA[4] = {}, aB[4] = {};
    #pragma unroll 1
    for (int ci = 0; ci < 4; ++ci) {
        const float4* wp = WP + 453 + ci * 9;
        #pragma unroll
        for (int kj = 0; kj < 3; ++kj) {
            const v2f* rE = &sdE[ci][ty + kj][tx];
            const v2f* rO = &sdO[ci][ty + kj][tx];
            v2f e0 = rE[0], o0 = rO[0], e1 = rE[1], o1 = rO[1];
            float4 W0 = wp[kj * 3], W1 = wp[kj * 3 + 1], W2 = wp[kj * 3 + 2];
            TAPW(W0, e0, o0)
            TAPW(W1, o0, e1)
            TAPW(W2, e1, o1)
        }
    }
    __builtin_amdgcn_s_setprio(0);

    const int oh = oh0 + ty, ow = ow0 + 2 * tx;
    if (oh >= Hh || ow >= Ww) return;
    float4 bias = g_bias, ssum = g_sum;
    float rs0 = rcpf(ssum.x), rs1 = rcpf(ssum.y),
          rs2 = rcpf(ssum.z), rs3 = rcpf(ssum.w);
    float4 xo, co;
    NC_EPI(aA, xo, co)
    float den7 = w7.x * co.x + w7.y * co.y + w7.z * co.z + w7.w * co.w;
    float nom7 = w7.x * xo.x * co.x + w7.y * xo.y * co.y
               + w7.z * xo.z * co.z + w7.w * xo.w * co.w;
    float zA = nom7 * rcpf(den7 + EPSN) + b7;
    size_t t = ((size_t)b * Hh + oh) * Ww + ow;
    if (ow + 1 < Ww) {
        NC_EPI(aB, xo, co)
        den7 = w7.x * co.x + w7.y * co.y + w7.z * co.z + w7.w * co.w;
        nom7 = w7.x * xo.x * co.x + w7.y * xo.y * co.y
             + w7.z * xo.z * co.z + w7.w * xo.w * co.w;
        float zB = nom7 * rcpf(den7 + EPSN) + b7;
        *(float2*)&zout[t] = make_float2(zA, zB);
    } else {
        zout[t] = zA;
    }
}

// ---------------------------------------------------------------------------
// Adaptive average pool (478,638) -> (480,640). Fully overwrites d_out.
// ---------------------------------------------------------------------------
__global__ __launch_bounds__(256) void apoolk(
    const float* __restrict__ in, float* __restrict__ out)
{
    const int HI = 478, WI = 638, HO = 480, WO = 640;
    int total = 8 * HO * WO;
    int i = blockIdx.x * 256 + threadIdx.x;
    if (i >= total) return;
    int ow = i % WO;
    int oh = (i / WO) % HO;
    int b  = i / (WO * HO);
    int sh = (oh * HI) / HO, eh = ((oh + 1) * HI + HO - 1) / HO;
    int sw = (ow * WI) / WO, ew = ((ow + 1) * WI + WO - 1) / WO;
    float s = 0.f;
    for (int ih = sh; ih < eh; ++ih)
        for (int iw = sw; iw < ew; ++iw)
            s += in[((size_t)b * HI + ih) * WI + iw];
    out[i] = s * rcpf((float)((eh - sh) * (ew - sw)));
}

// ---------------------------------------------------------------------------
extern "C" void kernel_launch(void* const* d_in, const int* in_sizes, int n_in,
                              void* d_out, int out_size, void* d_ws, size_t ws_size,
                              hipStream_t stream)
{
    const float* S   = (const float*)d_in[1];
    const float* w1  = (const float*)d_in[3];  const float* b1  = (const float*)d_in[4];
    const float* w2  = (const float*)d_in[5];  const float* b2  = (const float*)d_in[6];
    const float* w3  = (const float*)d_in[7];  const float* b3  = (const float*)d_in[8];
    const float* w4  = (const float*)d_in[9];  const float* b4  = (const float*)d_in[10];
    const float* w5  = (const float*)d_in[11]; const float* b5  = (const float*)d_in[12];
    const float* w6  = (const float*)d_in[13]; const float* b6  = (const float*)d_in[14];
    const float* w65 = (const float*)d_in[15]; const float* b65 = (const float*)d_in[16];
    const float* w7  = (const float*)d_in[17]; const float* b7  = (const float*)d_in[18];
    float* out = (float*)d_out;
    float* ws  = (float*)d_ws;

    const size_t FULL = 9830400, HALF = 2457600, QUAR = 614400, EIGH = 153600;
    float4 *A0 = (float4*)ws,              *A1 = (float4*)(ws + FULL),
           *A2 = (float4*)(ws + 2*FULL),   *A3 = (float4*)(ws + 3*FULL);
    float4 *P0 = (float4*)(ws + 4*FULL),            *P1 = (float4*)(ws + 4*FULL + HALF),
           *P2 = (float4*)(ws + 4*FULL + 2*HALF),   *P3 = (float4*)(ws + 4*FULL + 3*HALF);
    float4 *Q0 = (float4*)(ws + 4*FULL + 4*HALF),          *Q1 = (float4*)(ws + 4*FULL + 4*HALF + QUAR),
           *Q2 = (float4*)(ws + 4*FULL + 4*HALF + 2*QUAR), *Q3 = (float4*)(ws + 4*FULL + 4*HALF + 3*QUAR);
    float4 *E0 = (float4*)(ws + 4*FULL + 4*HALF + 4*QUAR),
           *E1 = (float4*)(ws + 4*FULL + 4*HALF + 4*QUAR + EIGH),
           *E2 = (float4*)(ws + 4*FULL + 4*HALF + 4*QUAR + 2*EIGH),
           *E3 = (float4*)(ws + 4*FULL + 4*HALF + 4*QUAR + 3*EIGH);

    float4* WP = (float4*)d_out;   // weight table; apoolk overwrites d_out last

    dim3 blk(16, 16);
    auto grd = [](int Ho, int Wo) { return dim3((Wo + 31) / 32, (Ho + 15) / 16, 8); };

    prepw<<<1, 256, 0, stream>>>(w1, b1, w2, b2, w3, b3, w4, b4, w5, b5,
                                 w6, b6, w65, b65, w7, b7, WP);

    // encoder, full res
    nconv5_first<<<grd(480, 640), blk, 0, stream>>>(S, WP, A0, A1, 480, 640);
    nconv5p4<false><<<grd(480, 640), blk, 0, stream>>>(A0, A1, WP, 27, A2, A3, nullptr, nullptr, 480, 640);
    nconv5p4<true ><<<grd(480, 640), blk, 0, stream>>>(A2, A3, WP, 129, A0, A1, P0, P1, 480, 640);  // x1,c1 + pooled
    // 1/2 scale
    nconv5p4<false><<<grd(240, 320), blk, 0, stream>>>(P0, P1, WP, 27, P2, P3, nullptr, nullptr, 240, 320);
    nconv5p4<true ><<<grd(240, 320), blk, 0, stream>>>(P2, P3, WP, 129, P0, P1, Q0, Q1, 240, 320);  // x2_ds + pooled
    // 1/4 scale
    nconv5p4<true ><<<grd(120, 160), blk, 0, stream>>>(Q0, Q1, WP, 27, Q2, Q3, E0, E1, 120, 160);   // x3_ds + pooled
    // 1/8 scale
    nconv5p4<false><<<grd(60, 80), blk, 0, stream>>>(E0, E1, WP, 27, E2, E3, nullptr, nullptr, 60, 80); // x4_ds
    // decoder
    nconv3cat<false, 1><<<grd(120, 160), blk, 0, stream>>>(Q2, Q3, E2, E3, WP, 231, Q0, Q1, 120, 160);
    nconv3cat<false, 1><<<grd(240, 320), blk, 0, stream>>>(P0, P1, Q0, Q1, WP, 305, P2, P3, 240, 320);
    nconv3cat<true , 0><<<grd(478, 638), blk, 0, stream>>>(A0, A1, P2, P3, WP, 379, A2, A3, 480, 640);
    nconv3p_w7<<<grd(478, 638), blk, 0, stream>>>(A2, A3, WP, (float*)A0, 478, 638);
    apoolk<<<(8 * 480 * 640 + 255) / 256, 256, 0, stream>>>((float*)A0, out);
}

// Round 17
// 299.306 us; speedup vs baseline: 1.0147x; 1.0147x over previous
//
#include <hip/hip_runtime.h>

// NConv depth-completion net, fp32. FINAL = R15 (299.6us measured), verbatim.
// R16's setprio experiment regressed (-1.3%: all waves enter FMA clusters
// simultaneously -> GEMM-lockstep-like null/negative, not attn-like win).
// Structure: prepw softplus-packs weights into d_out head (SGPR-uniform
// reads, pk_fma with "s" src0); packed float4 globals; parity-split LDS
// (conflict-free b64 taps); async-stage (T14); fused argmax-pool + w65+w7;
// 32x16 tiles; no launch_bounds minwaves; unroll 1 on ci loops.

#define EPSN 1e-20f

typedef float v2f __attribute__((ext_vector_type(2)));

__device__ __forceinline__ float softplusf(float x) {
    return fmaxf(x, 0.f) + log1pf(expf(-fabsf(x)));
}
__device__ __forceinline__ float rcpf(float x) { return __builtin_amdgcn_rcpf(x); }

// acc: a[0]={den0,den1} a[1]={den2,den3} a[2]={nom0,nom1} a[3]={nom2,nom3}
// Weight pairs come in as SGPRs (uniform), tap v={c,xc} in VGPRs.
__device__ __forceinline__ void tap4(v2f v, v2f w01, v2f w23, v2f* a)
{
    asm("v_pk_fma_f32 %0, %1, %2, %0 op_sel:[0,0,0] op_sel_hi:[1,0,1]"
        : "+v"(a[0]) : "s"(w01), "v"(v));
    asm("v_pk_fma_f32 %0, %1, %2, %0 op_sel:[0,0,0] op_sel_hi:[1,0,1]"
        : "+v"(a[1]) : "s"(w23), "v"(v));
    asm("v_pk_fma_f32 %0, %1, %2, %0 op_sel:[0,1,0] op_sel_hi:[1,1,1]"
        : "+v"(a[2]) : "s"(w01), "v"(v));
    asm("v_pk_fma_f32 %0, %1, %2, %0 op_sel:[0,1,0] op_sel_hi:[1,1,1]"
        : "+v"(a[3]) : "s"(w23), "v"(v));
}
#define TAPW(W, VA, VB)                                                     \
    { v2f w01_ = {(W).x, (W).y}, w23_ = {(W).z, (W).w};                     \
      tap4((VA), w01_, w23_, aA); tap4((VB), w01_, w23_, aB); }

#define NC_EPI(A, XO, CO)                                            \
    XO.x = A[2].x*rcpf(A[0].x+EPSN)+bias.x; CO.x = A[0].x*rs0;       \
    XO.y = A[2].y*rcpf(A[0].y+EPSN)+bias.y; CO.y = A[0].y*rs1;       \
    XO.z = A[3].x*rcpf(A[1].x+EPSN)+bias.z; CO.z = A[1].x*rs2;       \
    XO.w = A[3].y*rcpf(A[1].y+EPSN)+bias.w; CO.w = A[1].y*rs3;

#define NC_STORE_PACKED(HOUT, WOUT)                                         \
    {                                                                       \
        const int oh = oh0 + ty, ow = ow0 + 2 * tx;                         \
        if (oh < (HOUT) && ow < (WOUT)) {                                   \
            float4 bias = g_bias, ssum = g_sum;                             \
            float rs0=rcpf(ssum.x), rs1=rcpf(ssum.y),                       \
                  rs2=rcpf(ssum.z), rs3=rcpf(ssum.w);                       \
            size_t t = ((size_t)b * (HOUT) + oh) * (WOUT) + ow;             \
            float4 xo, co;                                                  \
            NC_EPI(aA, xo, co)                                              \
            xout4[t] = xo; cout4[t] = co;                                   \
            if (ow + 1 < (WOUT)) {                                          \
                NC_EPI(aB, xo, co)                                          \
                xout4[t+1] = xo; cout4[t+1] = co;                           \
            }                                                               \
        }                                                                   \
    }

#define STAGE_WRITE(SDE, SDO, LY, J, CA, XA, CB, XB)                 \
    SDE[0][LY][J] = (v2f){(CA).x, (XA).x * (CA).x};                  \
    SDE[1][LY][J] = (v2f){(CA).y, (XA).y * (CA).y};                  \
    SDE[2][LY][J] = (v2f){(CA).z, (XA).z * (CA).z};                  \
    SDE[3][LY][J] = (v2f){(CA).w, (XA).w * (CA).w};                  \
    SDO[0][LY][J] = (v2f){(CB).x, (XB).x * (CB).x};                  \
    SDO[1][LY][J] = (v2f){(CB).y, (XB).y * (CB).y};                  \
    SDO[2][LY][J] = (v2f){(CB).z, (XB).z * (CB).z};                  \
    SDO[3][LY][J] = (v2f){(CB).w, (XB).w * (CB).w};

// WP layout (float4 index):
//  w1:0(25) sum:25 bias:26 | w2:27(100) 127 128 | w3:129(100) 229 230
//  w4:231(72) 303 304 | w5:305(72) 377 378 | w6:379(72) 451 452
//  w65:453(36) 489 490 | w7sp:491 b7:492  -- total 493 float4 = 7888 B

__global__ __launch_bounds__(256) void prepw(
    const float* __restrict__ w1, const float* __restrict__ b1,
    const float* __restrict__ w2, const float* __restrict__ b2,
    const float* __restrict__ w3, const float* __restrict__ b3,
    const float* __restrict__ w4, const float* __restrict__ b4,
    const float* __restrict__ w5, const float* __restrict__ b5,
    const float* __restrict__ w6, const float* __restrict__ b6,
    const float* __restrict__ w65, const float* __restrict__ b65,
    const float* __restrict__ w7, const float* __restrict__ b7,
    float4* __restrict__ WP)
{
    const int tid = threadIdx.x;
    if (tid < 25)  WP[0 + tid]   = make_float4(softplusf(w1[tid]),  softplusf(w1[25 + tid]),
                                               softplusf(w1[50 + tid]), softplusf(w1[75 + tid]));
    if (tid < 100) WP[27 + tid]  = make_float4(softplusf(w2[tid]),  softplusf(w2[100 + tid]),
                                               softplusf(w2[200 + tid]), softplusf(w2[300 + tid]));
    if (tid < 100) WP[129 + tid] = make_float4(softplusf(w3[tid]),  softplusf(w3[100 + tid]),
                                               softplusf(w3[200 + tid]), softplusf(w3[300 + tid]));
    if (tid < 72)  WP[231 + tid] = make_float4(softplusf(w4[tid]),  softplusf(w4[72 + tid]),
                                               softplusf(w4[144 + tid]), softplusf(w4[216 + tid]));
    if (tid < 72)  WP[305 + tid] = make_float4(softplusf(w5[tid]),  softplusf(w5[72 + tid]),
                                               softplusf(w5[144 + tid]), softplusf(w5[216 + tid]));
    if (tid < 72)  WP[379 + tid] = make_float4(softplusf(w6[tid]),  softplusf(w6[72 + tid]),
                                               softplusf(w6[144 + tid]), softplusf(w6[216 + tid]));
    if (tid < 36)  WP[453 + tid] = make_float4(softplusf(w65[tid]), softplusf(w65[36 + tid]),
                                               softplusf(w65[72 + tid]), softplusf(w65[108 + tid]));
    if (tid == 0) {
        WP[26]  = make_float4(b1[0], b1[1], b1[2], b1[3]);
        WP[128] = make_float4(b2[0], b2[1], b2[2], b2[3]);
        WP[230] = make_float4(b3[0], b3[1], b3[2], b3[3]);
        WP[304] = make_float4(b4[0], b4[1], b4[2], b4[3]);
        WP[378] = make_float4(b5[0], b5[1], b5[2], b5[3]);
        WP[452] = make_float4(b6[0], b6[1], b6[2], b6[3]);
        WP[490] = make_float4(b65[0], b65[1], b65[2], b65[3]);
        WP[491] = make_float4(softplusf(w7[0]), softplusf(w7[1]),
                              softplusf(w7[2]), softplusf(w7[3]));
        WP[492] = make_float4(b7[0], 0.f, 0.f, 0.f);
    }
    __syncthreads();
    int base = -1, cnt = 0;
    if      (tid == 0) { base = 0;   cnt = 25;  }
    else if (tid == 1) { base = 27;  cnt = 100; }
    else if (tid == 2) { base = 129; cnt = 100; }
    else if (tid == 3) { base = 231; cnt = 72;  }
    else if (tid == 4) { base = 305; cnt = 72;  }
    else if (tid == 5) { base = 379; cnt = 72;  }
    else if (tid == 6) { base = 453; cnt = 36;  }
    if (base >= 0) {
        float4 s = make_float4(0.f, 0.f, 0.f, 0.f);
        for (int i = 0; i < cnt; ++i) {
            float4 w = WP[base + i];
            s.x += w.x; s.y += w.y; s.z += w.z; s.w += w.w;
        }
        WP[base + cnt] = s;
    }
}

// ---------------------------------------------------------------------------
// First 5x5 nconv: planar S in (c0 = S>0.01), packed out. Weights WP[0..].
// ---------------------------------------------------------------------------
__global__ __launch_bounds__(256) void nconv5_first(
    const float* __restrict__ S, const float4* __restrict__ WP,
    float4* __restrict__ xout4, float4* __restrict__ cout4,
    int Hh, int Ww)
{
    __shared__ v2f sdE[20][19], sdO[20][19];
    const int b = blockIdx.z;
    const int oh0 = blockIdx.y * 16, ow0 = blockIdx.x * 32;
    const int tx = threadIdx.x, ty = threadIdx.y, tid = ty * 16 + tx;

    const float4 g_sum = WP[25], g_bias = WP[26];

    for (int i = tid; i < 20 * 18; i += 256) {
        int ly = i / 18, j = i - ly * 18;
        int ih = oh0 - 2 + ly, iw = ow0 - 2 + 2 * j;
        float s0 = 0.f, s1 = 0.f;
        if ((unsigned)ih < (unsigned)Hh && iw >= 0 && iw < Ww - 1) {
            float2 t = *(const float2*)&S[((size_t)b * Hh + ih) * Ww + iw];
            s0 = t.x; s1 = t.y;
        }
        float c0 = (s0 > 0.01f) ? 1.f : 0.f;
        float c1 = (s1 > 0.01f) ? 1.f : 0.f;
        sdE[ly][j] = (v2f){c0, s0 * c0};
        sdO[ly][j] = (v2f){c1, s1 * c1};
    }
    __syncthreads();

    v2f aA[4] = {}, aB[4] = {};
    #pragma unroll
    for (int kj = 0; kj < 5; ++kj) {
        const v2f* rE = &sdE[ty + kj][tx];
        const v2f* rO = &sdO[ty + kj][tx];
        v2f e0 = rE[0], o0 = rO[0], e1 = rE[1], o1 = rO[1], e2 = rE[2], o2 = rO[2];
        const float4* wp = WP + kj * 5;
        float4 W0 = wp[0], W1 = wp[1], W2 = wp[2], W3 = wp[3], W4 = wp[4];
        TAPW(W0, e0, o0)
        TAPW(W1, o0, e1)
        TAPW(W2, e1, o1)
        TAPW(W3, o1, e2)
        TAPW(W4, e2, o2)
    }
    NC_STORE_PACKED(Hh, Ww)
}

// ---------------------------------------------------------------------------
// 5x5 nconv, CI=4, packed. Async-stage. Weights WP[wb..] (wb=27 or 129).
// POOL: fused 2x2 argmax pool.
// ---------------------------------------------------------------------------
template<bool POOL>
__global__ __launch_bounds__(256) void nconv5p4(
    const float4* __restrict__ xin4, const float4* __restrict__ cin4,
    const float4* __restrict__ WP, int wb,
    float4* __restrict__ xout4, float4* __restrict__ cout4,
    float4* __restrict__ xo_p, float4* __restrict__ co_p,
    int Hh, int Ww)
{
    __shared__ v2f sdE[4][20][19], sdO[4][20][19];
    const int b = blockIdx.z;
    const int oh0 = blockIdx.y * 16, ow0 = blockIdx.x * 32;
    const int tx = threadIdx.x, ty = threadIdx.y, tid = ty * 16 + tx;

    const float4 g_sum = WP[wb + 100], g_bias = WP[wb + 101];

    const float4 z = make_float4(0.f, 0.f, 0.f, 0.f);
    float4 cA0 = z, xA0 = z, cB0 = z, xB0 = z;
    float4 cA1 = z, xA1 = z, cB1 = z, xB1 = z;
    const bool t1ok = tid < 104;
    {
        int ly = tid / 18, j = tid - (tid / 18) * 18;
        int ih = oh0 - 2 + ly, iw = ow0 - 2 + 2 * j;
        if ((unsigned)ih < (unsigned)Hh) {
            size_t rb = ((size_t)b * Hh + ih) * Ww;
            if ((unsigned)iw < (unsigned)Ww)       { cA0 = cin4[rb + iw];     xA0 = xin4[rb + iw]; }
            if ((unsigned)(iw + 1) < (unsigned)Ww) { cB0 = cin4[rb + iw + 1]; xB0 = xin4[rb + iw + 1]; }
        }
    }
    if (t1ok) {
        int i = tid + 256;
        int ly = i / 18, j = i - ly * 18;
        int ih = oh0 - 2 + ly, iw = ow0 - 2 + 2 * j;
        if ((unsigned)ih < (unsigned)Hh) {
            size_t rb = ((size_t)b * Hh + ih) * Ww;
            if ((unsigned)iw < (unsigned)Ww)       { cA1 = cin4[rb + iw];     xA1 = xin4[rb + iw]; }
            if ((unsigned)(iw + 1) < (unsigned)Ww) { cB1 = cin4[rb + iw + 1]; xB1 = xin4[rb + iw + 1]; }
        }
    }
    {
        int ly = tid / 18, j = tid - (tid / 18) * 18;
        STAGE_WRITE(sdE, sdO, ly, j, cA0, xA0, cB0, xB0)
    }
    if (t1ok) {
        int i = tid + 256;
        int ly = i / 18, j = i - ly * 18;
        STAGE_WRITE(sdE, sdO, ly, j, cA1, xA1, cB1, xB1)
    }
    __syncthreads();

    v2f aA[4] = {}, aB[4] = {};
    #pragma unroll 1
    for (int ci = 0; ci < 4; ++ci) {
        const float4* wp = WP + wb + ci * 25;
        #pragma unroll
        for (int kj = 0; kj < 5; ++kj) {
            const v2f* rE = &sdE[ci][ty + kj][tx];
            const v2f* rO = &sdO[ci][ty + kj][tx];
            v2f e0 = rE[0], o0 = rO[0], e1 = rE[1], o1 = rO[1], e2 = rE[2], o2 = rO[2];
            float4 W0 = wp[kj * 5], W1 = wp[kj * 5 + 1], W2 = wp[kj * 5 + 2],
                   W3 = wp[kj * 5 + 3], W4 = wp[kj * 5 + 4];
            TAPW(W0, e0, o0)
            TAPW(W1, o0, e1)
            TAPW(W2, e1, o1)
            TAPW(W3, o1, e2)
            TAPW(W4, e2, o2)
        }
    }

    const int oh = oh0 + ty, ow = ow0 + 2 * tx;
    float4 bias = g_bias, ssum = g_sum;
    float rs0 = rcpf(ssum.x), rs1 = rcpf(ssum.y),
          rs2 = rcpf(ssum.z), rs3 = rcpf(ssum.w);
    float4 xoA, coA, xoB, coB;
    NC_EPI(aA, xoA, coA)
    NC_EPI(aB, xoB, coB)
    const bool rowok = oh < Hh, colA = ow < Ww, colB = ow + 1 < Ww;
    if (rowok && colA) {
        size_t t = ((size_t)b * Hh + oh) * Ww + ow;
        xout4[t] = xoA; cout4[t] = coA;
        if (colB) { xout4[t + 1] = xoB; cout4[t + 1] = coB; }
    }
    if (POOL) {
        float4 cb = coA, xb = xoA;
        if (coB.x > cb.x) { cb.x = coB.x; xb.x = xoB.x; }
        if (coB.y > cb.y) { cb.y = coB.y; xb.y = xoB.y; }
        if (coB.z > cb.z) { cb.z = coB.z; xb.z = xoB.z; }
        if (coB.w > cb.w) { cb.w = coB.w; xb.w = xoB.w; }
        float4 cb2, xb2;
        cb2.x = __shfl_down(cb.x, 16); xb2.x = __shfl_down(xb.x, 16);
        cb2.y = __shfl_down(cb.y, 16); xb2.y = __shfl_down(xb.y, 16);
        cb2.z = __shfl_down(cb.z, 16); xb2.z = __shfl_down(xb.z, 16);
        cb2.w = __shfl_down(cb.w, 16); xb2.w = __shfl_down(xb.w, 16);
        if (!(ty & 1) && rowok && colA) {
            if (cb2.x > cb.x) { cb.x = cb2.x; xb.x = xb2.x; }
            if (cb2.y > cb.y) { cb.y = cb2.y; xb.y = xb2.y; }
            if (cb2.z > cb.z) { cb.z = cb2.z; xb.z = xb2.z; }
            if (cb2.w > cb.w) { cb.w = cb2.w; xb.w = xb2.w; }
            cb.x *= 0.25f; cb.y *= 0.25f; cb.z *= 0.25f; cb.w *= 0.25f;
            size_t tp = ((size_t)b * (Hh >> 1) + (oh >> 1)) * (Ww >> 1) + (ow >> 1);
            xo_p[tp] = xb; co_p[tp] = cb;
        }
    }
}

// ---------------------------------------------------------------------------
// 3x3 nconv over concat{direct, up2}. Async-stage. Weights WP[wb..] (72).
// UP_FIRST: up occupies weight channels 0-3 (w6) else 4-7 (w4,w5).
// ---------------------------------------------------------------------------
template<bool UP_FIRST, int PAD>
__global__ __launch_bounds__(256) void nconv3cat(
    const float4* __restrict__ xd4, const float4* __restrict__ cd4,
    const float4* __restrict__ xu4, const float4* __restrict__ cu4,
    const float4* __restrict__ WP, int wb,
    float4* __restrict__ xout4, float4* __restrict__ cout4,
    int Hin, int Win)
{
    __shared__ v2f sdE[4][18][18], sdO[4][18][18];
    __shared__ v2f sup[4][10][19];
    const int Hout = Hin - 2 + 2 * PAD, Wout = Win - 2 + 2 * PAD;
    const int Hu = Hin / 2, Wu = Win / 2;
    const int b = blockIdx.z;
    const int oh0 = blockIdx.y * 16, ow0 = blockIdx.x * 32;
    const int tx = threadIdx.x, ty = threadIdx.y, tid = ty * 16 + tx;

    const float4 g_sum = WP[wb + 72], g_bias = WP[wb + 73];

    const float4 z = make_float4(0.f, 0.f, 0.f, 0.f);
    float4 cA0 = z, xA0 = z, cB0 = z, xB0 = z;
    float4 cA1 = z, xA1 = z, cB1 = z, xB1 = z;
    float4 cU = z, xU = z;
    const bool t1ok = tid < 50, upok = tid < 180;
    {
        int ly = tid / 17, j = tid - (tid / 17) * 17;
        int ih = oh0 - PAD + ly, iw = ow0 - PAD + 2 * j;
        if ((unsigned)ih < (unsigned)Hin) {
            size_t rb = ((size_t)b * Hin + ih) * Win;
            if ((unsigned)iw < (unsigned)Win)       { cA0 = cd4[rb + iw];     xA0 = xd4[rb + iw]; }
            if ((unsigned)(iw + 1) < (unsigned)Win) { cB0 = cd4[rb + iw + 1]; xB0 = xd4[rb + iw + 1]; }
        }
    }
    if (t1ok) {
        int i = tid + 256;
        int ly = i / 17, j = i - ly * 17;
        int ih = oh0 - PAD + ly, iw = ow0 - PAD + 2 * j;
        if ((unsigned)ih < (unsigned)Hin) {
            size_t rb = ((size_t)b * Hin + ih) * Win;
            if ((unsigned)iw < (unsigned)Win)       { cA1 = cd4[rb + iw];     xA1 = xd4[rb + iw]; }
            if ((unsigned)(iw + 1) < (unsigned)Win) { cB1 = cd4[rb + iw + 1]; xB1 = xd4[rb + iw + 1]; }
        }
    }
    const int ru0 = (oh0 - PAD) >> 1, cu0 = (ow0 - PAD) >> 1;
    if (upok) {
        int r = tid / 18, k = tid - (tid / 18) * 18;
        int ur = ru0 + r, uc = cu0 + k;
        if ((unsigned)ur < (unsigned)Hu && (unsigned)uc < (unsigned)Wu) {
            size_t t = ((size_t)b * Hu + ur) * Wu + uc;
            cU = cu4[t]; xU = xu4[t];
        }
    }
    {
        int ly = tid / 17, j = tid - (tid / 17) * 17;
        STAGE_WRITE(sdE, sdO, ly, j, cA0, xA0, cB0, xB0)
    }
    if (t1ok) {
        int i = tid + 256;
        int ly = i / 17, j = i - ly * 17;
        STAGE_WRITE(sdE, sdO, ly, j, cA1, xA1, cB1, xB1)
    }
    if (upok) {
        int r = tid / 18, k = tid - (tid / 18) * 18;
        sup[0][r][k] = (v2f){cU.x, xU.x * cU.x};
        sup[1][r][k] = (v2f){cU.y, xU.y * cU.y};
        sup[2][r][k] = (v2f){cU.z, xU.z * cU.z};
        sup[3][r][k] = (v2f){cU.w, xU.w * cU.w};
    }
    __syncthreads();

    v2f aA[4] = {}, aB[4] = {};
    #pragma unroll 1
    for (int ci = 0; ci < 4; ++ci) {
        const int chD = UP_FIRST ? ci + 4 : ci;
        const int chU = UP_FIRST ? ci : ci + 4;
        #pragma unroll
        for (int kj = 0; kj < 3; ++kj) {
            const v2f* rE = &sdE[ci][ty + kj][tx];
            const v2f* rO = &sdO[ci][ty + kj][tx];
            v2f e0 = rE[0], o0 = rO[0], e1 = rE[1], o1 = rO[1];
            const float4* wp = WP + wb + chD * 9 + kj * 3;
            float4 W0 = wp[0], W1 = wp[1], W2 = wp[2];
            TAPW(W0, e0, o0)
            TAPW(W1, o0, e1)
            TAPW(W2, e1, o1)
        }
        #pragma unroll
        for (int kj = 0; kj < 3; ++kj) {
            int lyu = (ty + kj + PAD) >> 1;
            const v2f* ru = &sup[ci][lyu][tx];
            v2f u0 = ru[0], u1 = ru[1];
            v2f q0, q1, q2, q3;
            if (PAD == 1) {
                v2f u2 = ru[2];
                q0 = u0; q1 = u1; q2 = u1; q3 = u2;
            } else {
                q0 = u0; q1 = u0; q2 = u1; q3 = u1;
            }
            const float4* wp = WP + wb + chU * 9 + kj * 3;
            float4 W0 = wp[0], W1 = wp[1], W2 = wp[2];
            TAPW(W0, q0, q1)
            TAPW(W1, q1, q2)
            TAPW(W2, q2, q3)
        }
    }
    NC_STORE_PACKED(Hout, Wout)
}

// ---------------------------------------------------------------------------
// 3x3 nconv 4->4 pad=1 (w65) + 1x1 nconv (w7) -> scalar z. Async-stage.
// Weights WP[453..], w7 WP[491], b7 WP[492].x.
// ---------------------------------------------------------------------------
__global__ __launch_bounds__(256) void nconv3p_w7(
    const float4* __restrict__ xin4, const float4* __restrict__ cin4,
    const float4* __restrict__ WP,
    float* __restrict__ zout,
    int Hh, int Ww)
{
    __shared__ v2f sdE[4][18][18], sdO[4][18][18];
    const int b = blockIdx.z;
    const int oh0 = blockIdx.y * 16, ow0 = blockIdx.x * 32;
    const int tx = threadIdx.x, ty = threadIdx.y, tid = ty * 16 + tx;

    const float4 g_sum = WP[489], g_bias = WP[490];
    const float4 w7 = WP[491];
    const float b7 = WP[492].x;

    const float4 z = make_float4(0.f, 0.f, 0.f, 0.f);
    float4 cA0 = z, xA0 = z, cB0 = z, xB0 = z;
    float4 cA1 = z, xA1 = z, cB1 = z, xB1 = z;
    const bool t1ok = tid < 50;
    {
        int ly = tid / 17, j = tid - (tid / 17) * 17;
        int ih = oh0 - 1 + ly, iw = ow0 - 1 + 2 * j;
        if ((unsigned)ih < (unsigned)Hh) {
            size_t rb = ((size_t)b * Hh + ih) * Ww;
            if ((unsigned)iw < (unsigned)Ww)       { cA0 = cin4[rb + iw];     xA0 = xin4[rb + iw]; }
            if ((unsigned)(iw + 1) < (unsigned)Ww) { cB0 = cin4[rb + iw + 1]; xB0 = xin4[rb + iw + 1]; }
        }
    }
    if (t1ok) {
        int i = tid + 256;
        int ly = i / 17, j = i - ly * 17;
        int ih = oh0 - 1 + ly, iw = ow0 - 1 + 2 * j;
        if ((unsigned)ih < (unsigned)Hh) {
            size_t rb = ((size_t)b * Hh + ih) * Ww;
            if ((unsigned)iw < (unsigned)Ww)       { cA1 = cin4[rb + iw];     xA1 = xin4[rb + iw]; }
            if ((unsigned)(iw + 1) < (unsigned)Ww) { cB1 = cin4[rb + iw + 1]; xB1 = xin4[rb + iw + 1]; }
        }
    }
    {
        int ly = tid / 17, j = tid - (tid / 17) * 17;
        STAGE_WRITE(sdE, sdO, ly, j, cA0, xA0, cB0, xB0)
    }
    if (t1ok) {
        int i = tid + 256;
        int ly = i / 17, j = i - ly * 17;
        STAGE_WRITE(sdE, sdO, ly, j, cA1, xA1, cB1, xB1)
    }
    __syncthreads();

    v2f aA[4] = {}, aB[4] = {};
    #pragma unroll 1
    for (int ci = 0; ci < 4; ++ci) {
        const float4* wp = WP + 453 + ci * 9;
        #pragma unroll
        for (int kj = 0; kj < 3; ++kj) {
            const v2f* rE = &sdE[ci][ty + kj][tx];
            const v2f* rO = &sdO[ci][ty + kj][tx];
            v2f e0 = rE[0], o0 = rO[0], e1 = rE[1], o1 = rO[1];
            float4 W0 = wp[kj * 3], W1 = wp[kj * 3 + 1], W2 = wp[kj * 3 + 2];
            TAPW(W0, e0, o0)
            TAPW(W1, o0, e1)
            TAPW(W2, e1, o1)
        }
    }

    const int oh = oh0 + ty, ow = ow0 + 2 * tx;
    if (oh >= Hh || ow >= Ww) return;
    float4 bias = g_bias, ssum = g_sum;
    float rs0 = rcpf(ssum.x), rs1 = rcpf(ssum.y),
          rs2 = rcpf(ssum.z), rs3 = rcpf(ssum.w);
    float4 xo, co;
    NC_EPI(aA, xo, co)
    float den7 = w7.x * co.x + w7.y * co.y + w7.z * co.z + w7.w * co.w;
    float nom7 = w7.x * xo.x * co.x + w7.y * xo.y * co.y
               + w7.z * xo.z * co.z + w7.w * xo.w * co.w;
    float zA = nom7 * rcpf(den7 + EPSN) + b7;
    size_t t = ((size_t)b * Hh + oh) * Ww + ow;
    if (ow + 1 < Ww) {
        NC_EPI(aB, xo, co)
        den7 = w7.x * co.x + w7.y * co.y + w7.z * co.z + w7.w * co.w;
        nom7 = w7.x * xo.x * co.x + w7.y * xo.y * co.y
             + w7.z * xo.z * co.z + w7.w * xo.w * co.w;
        float zB = nom7 * rcpf(den7 + EPSN) + b7;
        *(float2*)&zout[t] = make_float2(zA, zB);
    } else {
        zout[t] = zA;
    }
}

// ---------------------------------------------------------------------------
// Adaptive average pool (478,638) -> (480,640). Fully overwrites d_out.
// ---------------------------------------------------------------------------
__global__ __launch_bounds__(256) void apoolk(
    const float* __restrict__ in, float* __restrict__ out)
{
    const int HI = 478, WI = 638, HO = 480, WO = 640;
    int total = 8 * HO * WO;
    int i = blockIdx.x * 256 + threadIdx.x;
    if (i >= total) return;
    int ow = i % WO;
    int oh = (i / WO) % HO;
    int b  = i / (WO * HO);
    int sh = (oh * HI) / HO, eh = ((oh + 1) * HI + HO - 1) / HO;
    int sw = (ow * WI) / WO, ew = ((ow + 1) * WI + WO - 1) / WO;
    float s = 0.f;
    for (int ih = sh; ih < eh; ++ih)
        for (int iw = sw; iw < ew; ++iw)
            s += in[((size_t)b * HI + ih) * WI + iw];
    out[i] = s * rcpf((float)((eh - sh) * (ew - sw)));
}

// ---------------------------------------------------------------------------
extern "C" void kernel_launch(void* const* d_in, const int* in_sizes, int n_in,
                              void* d_out, int out_size, void* d_ws, size_t ws_size,
                              hipStream_t stream)
{
    const float* S   = (const float*)d_in[1];
    const float* w1  = (const float*)d_in[3];  const float* b1  = (const float*)d_in[4];
    const float* w2  = (const float*)d_in[5];  const float* b2  = (const float*)d_in[6];
    const float* w3  = (const float*)d_in[7];  const float* b3  = (const float*)d_in[8];
    const float* w4  = (const float*)d_in[9];  const float* b4  = (const float*)d_in[10];
    const float* w5  = (const float*)d_in[11]; const float* b5  = (const float*)d_in[12];
    const float* w6  = (const float*)d_in[13]; const float* b6  = (const float*)d_in[14];
    const float* w65 = (const float*)d_in[15]; const float* b65 = (const float*)d_in[16];
    const float* w7  = (const float*)d_in[17]; const float* b7  = (const float*)d_in[18];
    float* out = (float*)d_out;
    float* ws  = (float*)d_ws;

    const size_t FULL = 9830400, HALF = 2457600, QUAR = 614400, EIGH = 153600;
    float4 *A0 = (float4*)ws,              *A1 = (float4*)(ws + FULL),
           *A2 = (float4*)(ws + 2*FULL),   *A3 = (float4*)(ws + 3*FULL);
    float4 *P0 = (float4*)(ws + 4*FULL),            *P1 = (float4*)(ws + 4*FULL + HALF),
           *P2 = (float4*)(ws + 4*FULL + 2*HALF),   *P3 = (float4*)(ws + 4*FULL + 3*HALF);
    float4 *Q0 = (float4*)(ws + 4*FULL + 4*HALF),          *Q1 = (float4*)(ws + 4*FULL + 4*HALF + QUAR),
           *Q2 = (float4*)(ws + 4*FULL + 4*HALF + 2*QUAR), *Q3 = (float4*)(ws + 4*FULL + 4*HALF + 3*QUAR);
    float4 *E0 = (float4*)(ws + 4*FULL + 4*HALF + 4*QUAR),
           *E1 = (float4*)(ws + 4*FULL + 4*HALF + 4*QUAR + EIGH),
           *E2 = (float4*)(ws + 4*FULL + 4*HALF + 4*QUAR + 2*EIGH),
           *E3 = (float4*)(ws + 4*FULL + 4*HALF + 4*QUAR + 3*EIGH);

    float4* WP = (float4*)d_out;   // weight table; apoolk overwrites d_out last

    dim3 blk(16, 16);
    auto grd = [](int Ho, int Wo) { return dim3((Wo + 31) / 32, (Ho + 15) / 16, 8); };

    prepw<<<1, 256, 0, stream>>>(w1, b1, w2, b2, w3, b3, w4, b4, w5, b5,
                                 w6, b6, w65, b65, w7, b7, WP);

    // encoder, full res
    nconv5_first<<<grd(480, 640), blk, 0, stream>>>(S, WP, A0, A1, 480, 640);
    nconv5p4<false><<<grd(480, 640), blk, 0, stream>>>(A0, A1, WP, 27, A2, A3, nullptr, nullptr, 480, 640);
    nconv5p4<true ><<<grd(480, 640), blk, 0, stream>>>(A2, A3, WP, 129, A0, A1, P0, P1, 480, 640);  // x1,c1 + pooled
    // 1/2 scale
    nconv5p4<false><<<grd(240, 320), blk, 0, stream>>>(P0, P1, WP, 27, P2, P3, nullptr, nullptr, 240, 320);
    nconv5p4<true ><<<grd(240, 320), blk, 0, stream>>>(P2, P3, WP, 129, P0, P1, Q0, Q1, 240, 320);  // x2_ds + pooled
    // 1/4 scale
    nconv5p4<true ><<<grd(120, 160), blk, 0, stream>>>(Q0, Q1, WP, 27, Q2, Q3, E0, E1, 120, 160);   // x3_ds + pooled
    // 1/8 scale
    nconv5p4<false><<<grd(60, 80), blk, 0, stream>>>(E0, E1, WP, 27, E2, E3, nullptr, nullptr, 60, 80); // x4_ds
    // decoder
    nconv3cat<false, 1><<<grd(120, 160), blk, 0, stream>>>(Q2, Q3, E2, E3, WP, 231, Q0, Q1, 120, 160);
    nconv3cat<false, 1><<<grd(240, 320), blk, 0, stream>>>(P0, P1, Q0, Q1, WP, 305, P2, P3, 240, 320);
    nconv3cat<true , 0><<<grd(478, 638), blk, 0, stream>>>(A0, A1, P2, P3, WP, 379, A2, A3, 480, 640);
    nconv3p_w7<<<grd(478, 638), blk, 0, stream>>>(A2, A3, WP, (float*)A0, 478, 638);
    apoolk<<<(8 * 480 * 640 + 255) / 256, 256, 0, stream>>>((float*)A0, out);
}